// Round 7
// baseline (1090.481 us; speedup 1.0000x reference)
//
#include <hip/hip_runtime.h>
#include <hip/hip_bf16.h>
#include <cstddef>
#include <cstdint>

// Problem constants (fixed by the reference)
#define N_TOK 16384     // B*S = 32*512
#define H_    2048
#define FP_   1024
#define SP_   1024
#define C_    2050      // 2 + FP + SP, prob_all row stride

#define BM 128
#define BN 128
#define BK 64
#define KP 72           // padded stride for the FALLBACK fused kernel only

typedef short bf16x8 __attribute__((ext_vector_type(8)));  // 8 bf16 = 4 VGPRs
typedef float f32x4  __attribute__((ext_vector_type(4)));  // 4 fp32 acc
typedef float f4     __attribute__((ext_vector_type(4)));  // for nt load
typedef float f2     __attribute__((ext_vector_type(2)));  // for nt store

__device__ __forceinline__ unsigned pack_bf2(float a, float b) {
  __hip_bfloat16 x = __float2bfloat16(a);
  __hip_bfloat16 y = __float2bfloat16(b);
  unsigned short ux, uy;
  __builtin_memcpy(&ux, &x, 2);
  __builtin_memcpy(&uy, &y, 2);
  return (unsigned)ux | ((unsigned)uy << 16);
}

__device__ __forceinline__ unsigned short f2bf(float f) {
  __hip_bfloat16 h = __float2bfloat16(f);
  unsigned short u;
  __builtin_memcpy(&u, &h, 2);
  return u;
}

__device__ __forceinline__ float bf2f(unsigned short u) {
  unsigned v = (unsigned)u << 16;
  float f;
  __builtin_memcpy(&f, &v, 4);
  return f;
}

// ---------------------------------------------------------------------------
// FAST PATH kernel 1: fp32 -> bf16 pre-convert of X and W into d_ws, fusing
// the end-head dot (fp32-exact) into the X pass. NT loads on read-once fp32.
// NEW this round: zeroes the 128 per-panel ticket counters (mat[p*128*C_+1],
// a slot untouched by the GEMM C-write) so the fused epilogue can count
// finished col-blocks. Stream order guarantees the zeroes land before gemm.
// ---------------------------------------------------------------------------
__global__ __launch_bounds__(256) void convert_kernel(
    const float* __restrict__ X,
    const float* __restrict__ W_hcw, const float* __restrict__ W_roo,
    const float* __restrict__ W_end, const float* __restrict__ b_end,
    unsigned short* __restrict__ Xb, unsigned short* __restrict__ Wb,
    float* __restrict__ mat)
{
  const int wave = threadIdx.x >> 6;
  const int lane = threadIdx.x & 63;
  const int row  = (blockIdx.x << 2) + wave;
  const bool isX = row < N_TOK;
  const float* src;
  unsigned short* dst;
  if (isX) {
    src = X + (size_t)row * H_;
    dst = Xb + (size_t)row * H_;
  } else {
    const int m = row - N_TOK;
    src = (m < FP_) ? (W_hcw + (size_t)m * H_) : (W_roo + (size_t)(m - FP_) * H_);
    dst = Wb + (size_t)m * H_;
  }
  float s = 0.f;
#pragma unroll
  for (int i = 0; i < 8; ++i) {
    const int e = (lane << 2) + (i << 8);      // lane*4 + i*256: coalesced
    f4 v = __builtin_nontemporal_load((const f4*)(src + e));
    uint2 p;
    p.x = pack_bf2(v[0], v[1]);
    p.y = pack_bf2(v[2], v[3]);
    *(uint2*)(dst + e) = p;                     // Xb/Wb re-read by GEMM: cached
    if (isX) {                                  // wave-uniform branch
      float4 w = *(const float4*)(W_end + e);   // 8 KB, reused: cached
      s += v[0] * w.x + v[1] * w.y + v[2] * w.z + v[3] * w.w;
    }
  }
  if (isX) {
#pragma unroll
    for (int o = 32; o; o >>= 1) s += __shfl_xor(s, o);
    if (lane == 0) {
      mat[(size_t)row * C_] = s + b_end[0];
      if ((row & 127) == 0) mat[(size_t)row * C_ + 1] = 0.0f;  // panel ticket=0
    }
  }
}

// ---------------------------------------------------------------------------
// FAST PATH kernel 2: bf16 MFMA GEMM (proven 128^2 2-phase structure, inner
// loop untouched) + NEW: FUSED EPILOGUE via per-panel ticket. After its
// C-write, each of a panel's 16 col-blocks does threadfence + atomicAdd on
// the panel counter (CUTLASS serial-splitK pattern, wait-free). The block
// drawing ticket 15 runs the softmax/sigmoid epilogue for the panel's 128
// tokens — overlapped with still-running GEMM blocks of later panels, with
// the panel's logits L2/L3-warm (its 16 blocks are bid-contiguous).
// ---------------------------------------------------------------------------
__global__ __launch_bounds__(256) void gemm_lds_kernel(
    const unsigned short* __restrict__ Xb, const unsigned short* __restrict__ Wb,
    const float* __restrict__ b_hcw, const float* __restrict__ b_roo,
    const int* __restrict__ pY, const int* __restrict__ Yf,
    float* __restrict__ logp, float* __restrict__ mat)
{
  __shared__ __align__(16) unsigned short As[BM * BK];   // 16 KB
  __shared__ __align__(16) unsigned short Bs[BN * BK];   // 16 KB
  __shared__ int ticket_s;

  const int bid = blockIdx.x;              // 0..2047; panel p = blocks 16p..16p+15
  const int xcd = bid & 7;
  const int loc = bid >> 3;
  const int c0 = (((xcd << 1) | (loc & 1))) * BN;   // col-tile 0..15
  const int n0 = (loc >> 1) * BM;                    // row-panel 0..127
  const float* bias = (c0 < FP_) ? (b_hcw + c0) : (b_roo + (c0 - FP_));

  const int t    = threadIdx.x;
  const int wave = t >> 6;
  const int lane = t & 63;
  const int wy   = wave >> 1;
  const int wx   = wave & 1;
  const int quad = lane >> 4;
  const int l16  = lane & 15;

  // staging map: LDS flat byte f = r*4096 + t*16 -> (row = r*32 + t/8,
  // pos = t&7). That slot must hold global chunk pos ^ (row&7).
  const int srow   = t >> 3;                       // 0..31
  const int gchunk = (t & 7) ^ (srow & 7);         // swizzled global chunk
  const unsigned short* gA = Xb + (size_t)(n0 + srow) * H_ + (gchunk << 3);
  const unsigned short* gB = Wb + (size_t)(c0 + srow) * H_ + (gchunk << 3);

  f32x4 acc[4][4];
#pragma unroll
  for (int i = 0; i < 4; ++i)
#pragma unroll
    for (int j = 0; j < 4; ++j)
#pragma unroll
      for (int r = 0; r < 4; ++r) acc[i][j][r] = 0.f;

  for (int k0 = 0; k0 < H_; k0 += BK) {
#pragma unroll
    for (int r = 0; r < 4; ++r) {
      __builtin_amdgcn_global_load_lds(
          (const __attribute__((address_space(1))) unsigned int*)(gA + (size_t)(r * 32) * H_ + k0),
          (__attribute__((address_space(3))) unsigned int*)(&As[(r * 32 + srow) * BK + ((t & 7) << 3)]),
          16, 0, 0);
      __builtin_amdgcn_global_load_lds(
          (const __attribute__((address_space(1))) unsigned int*)(gB + (size_t)(r * 32) * H_ + k0),
          (__attribute__((address_space(3))) unsigned int*)(&Bs[(r * 32 + srow) * BK + ((t & 7) << 3)]),
          16, 0, 0);
    }
    __syncthreads();   // drains vmcnt before barrier (compiler-enforced)

#pragma unroll
    for (int kk = 0; kk < 2; ++kk) {
      bf16x8 af[4], bfr[4];
      const int sw = l16 & 7;                      // row&7 for both A and B rows
#pragma unroll
      for (int i = 0; i < 4; ++i) {
        const int pos = ((kk << 2) + quad) ^ sw;
        af[i] = *(const bf16x8*)&As[(wy * 64 + i * 16 + l16) * BK + (pos << 3)];
      }
#pragma unroll
      for (int j = 0; j < 4; ++j) {
        const int pos = ((kk << 2) + quad) ^ sw;
        bfr[j] = *(const bf16x8*)&Bs[(wx * 64 + j * 16 + l16) * BK + (pos << 3)];
      }
#pragma unroll
      for (int i = 0; i < 4; ++i)
#pragma unroll
        for (int j = 0; j < 4; ++j)
          acc[i][j] = __builtin_amdgcn_mfma_f32_16x16x32_bf16(af[i], bfr[j], acc[i][j], 0, 0, 0);
    }
    __syncthreads();
  }

  // C/D layout: col=lane&15, row=quad*4+reg (m89-verified). Store bf16.
  float bj[4];
#pragma unroll
  for (int j = 0; j < 4; ++j) bj[j] = bias[wx * 64 + j * 16 + l16];
#pragma unroll
  for (int i = 0; i < 4; ++i) {
#pragma unroll
    for (int r = 0; r < 4; ++r) {
      const int row = n0 + wy * 64 + i * 16 + quad * 4 + r;
      unsigned short* dst =
          (unsigned short*)(mat + (size_t)row * C_ + 4) + c0 + wx * 64 + l16;
#pragma unroll
      for (int j = 0; j < 4; ++j) dst[j * 16] = f2bf(acc[i][j][r] + bj[j]);
    }
  }

  // ---- panel ticket: release logit stores, count finished col-blocks ------
  __threadfence();                 // release: all this block's stores
  __syncthreads();                 // all threads' stores fenced before the add
  if (t == 0)
    ticket_s = atomicAdd((int*)(mat + (size_t)n0 * C_ + 1), 1);  // device scope
  __syncthreads();
  if (ticket_s != 15) return;      // block-uniform

  // ---- FUSED EPILOGUE (last col-block of this panel): 128 tokens ----------
  __threadfence();                 // acquire: see the other 15 blocks' logits
  const int n_base = n0 + wave * 32;   // each wave: 32 consecutive tokens
  for (int it = 0; it < 32; ++it) {
    const int n = n_base + it;
    float* row = mat + (size_t)n * C_;
    const unsigned short* lg = (const unsigned short*)(row + 4);  // 2048 bf16

    const int py = pY[n];
    const int y  = Yf[n];
    const float z = row[0];
    const int ih = min(max(y - 2, 0), FP_ - 1);
    const int ir = min(max(y - 2 - FP_, 0), SP_ - 1);
    const float lh = bf2f(lg[ih]);          // same-address broadcast load
    const float lr = bf2f(lg[FP_ + ir]);

    // read: iteration i covers classes [i*256, i*256+256) (contiguous 512B)
    uint2 u[8];
#pragma unroll
    for (int i = 0; i < 8; ++i)
      u[i] = *(const uint2*)(lg + (i << 8) + (lane << 2));

    float e[32];
    float sh = 0.f, sr = 0.f;
#pragma unroll
    for (int i = 0; i < 8; ++i) {
      const float e0 = __expf(bf2f((unsigned short)(u[i].x & 0xffffu)));
      const float e1 = __expf(bf2f((unsigned short)(u[i].x >> 16)));
      const float e2 = __expf(bf2f((unsigned short)(u[i].y & 0xffffu)));
      const float e3 = __expf(bf2f((unsigned short)(u[i].y >> 16)));
      e[4 * i + 0] = e0; e[4 * i + 1] = e1; e[4 * i + 2] = e2; e[4 * i + 3] = e3;
      if (i < 4) sh += e0 + e1 + e2 + e3;
      else       sr += e0 + e1 + e2 + e3;
    }
#pragma unroll
    for (int o = 32; o; o >>= 1) sh += __shfl_xor(sh, o);
#pragma unroll
    for (int o = 32; o; o >>= 1) sr += __shfl_xor(sr, o);
    const float Sh = sh, Sr = sr;

    // reads of this row must land before in-place writes below (same wave)
    asm volatile("s_waitcnt vmcnt(0)" ::: "memory");

    const float sig = 1.f / (1.f + __expf(-z));
    const float ne  = 1.f - sig;
    const float sch = (py == 1) ? ne / Sh : 0.f;
    const float scr = (py == 2) ? ne / Sr : 0.f;
#pragma unroll
    for (int i = 0; i < 8; ++i) {
      const float sc = (i < 4) ? sch : scr;
      f2* wp = (f2*)(row + 2 + (i << 8) + (lane << 2));  // 8B aligned
      f2 v0 = {e[4 * i + 0] * sc, e[4 * i + 1] * sc};
      f2 v1 = {e[4 * i + 2] * sc, e[4 * i + 3] * sc};
      __builtin_nontemporal_store(v0, wp);
      __builtin_nontemporal_store(v1, wp + 1);
    }
    if (lane == 0) {
      const float ev = (py == 0) ? sig : 0.f;
      row[0] = ev;
      row[1] = ev;
      const float l1p   = log1pf(__expf(-fabsf(z)));
      const float sp_z  = fmaxf(z, 0.f)  + l1p;
      const float sp_mz = fmaxf(-z, 0.f) + l1p;
      float lp;
      if      (py == 0) lp = -sp_mz;
      else if (py == 1) lp = (lh - __logf(Sh)) - sp_z;
      else if (py == 2) lp = (lr - __logf(Sr)) - sp_z;
      else              lp = 0.f;
      logp[n] = lp;
    }
  }
}

// ---------------------------------------------------------------------------
// FALLBACK kernels (used only if ws_size is too small). Same bf16-logit
// output convention as the fast path; the standalone epilogue serves them.
// ---------------------------------------------------------------------------
__global__ __launch_bounds__(256) void end_head_kernel(
    const float* __restrict__ X, const float* __restrict__ W_end,
    const float* __restrict__ b_end, float* __restrict__ mat)
{
  const int wave = threadIdx.x >> 6;
  const int lane = threadIdx.x & 63;
  const int n = (blockIdx.x << 2) + wave;
  const float* x = X + (size_t)n * H_;
  float s = 0.f;
#pragma unroll
  for (int i = 0; i < 8; ++i) {
    const int e = (lane + (i << 6)) << 2;
    float4 xv = *(const float4*)(x + e);
    float4 wv = *(const float4*)(W_end + e);
    s += xv.x * wv.x + xv.y * wv.y + xv.z * wv.z + xv.w * wv.w;
  }
#pragma unroll
  for (int o = 32; o; o >>= 1) s += __shfl_xor(s, o);
  if (lane == 0) mat[(size_t)n * C_] = s + b_end[0];
}

__global__ __launch_bounds__(256) void logits_gemm_fused(
    const float* __restrict__ X,
    const float* __restrict__ W_hcw, const float* __restrict__ W_roo,
    const float* __restrict__ b_hcw, const float* __restrict__ b_roo,
    float* __restrict__ mat)
{
  __shared__ __align__(16) unsigned short As[BM * KP];
  __shared__ __align__(16) unsigned short Bs[BN * KP];

  const int c0 = blockIdx.x * BN;
  const int n0 = blockIdx.y * BM;
  const float* Wbase = (c0 < FP_) ? (W_hcw + (size_t)c0 * H_)
                                  : (W_roo + (size_t)(c0 - FP_) * H_);
  const float* bias  = (c0 < FP_) ? (b_hcw + c0) : (b_roo + (c0 - FP_));

  const int t    = threadIdx.x;
  const int wave = t >> 6;
  const int lane = t & 63;
  const int wy   = wave >> 1;
  const int wx   = wave & 1;
  const int quad = lane >> 4;
  const int l16  = lane & 15;
  const int tq = t & 3;
  const int tr = t >> 2;

  f32x4 acc[4][4];
#pragma unroll
  for (int i = 0; i < 4; ++i)
#pragma unroll
    for (int j = 0; j < 4; ++j)
#pragma unroll
      for (int r = 0; r < 4; ++r) acc[i][j][r] = 0.f;

  for (int k0 = 0; k0 < H_; k0 += BK) {
#pragma unroll
    for (int p = 0; p < 2; ++p) {
      const int row = tr + (p << 6);
      const float4* xs = (const float4*)(X + (size_t)(n0 + row) * H_ + k0 + (tq << 4));
      const float4* ws = (const float4*)(Wbase + (size_t)row * H_ + k0 + (tq << 4));
      float4 x0 = xs[0], x1 = xs[1], x2 = xs[2], x3 = xs[3];
      float4 w0 = ws[0], w1 = ws[1], w2 = ws[2], w3 = ws[3];
      uint4 ua0 = {pack_bf2(x0.x, x0.y), pack_bf2(x0.z, x0.w),
                   pack_bf2(x1.x, x1.y), pack_bf2(x1.z, x1.w)};
      uint4 ua1 = {pack_bf2(x2.x, x2.y), pack_bf2(x2.z, x2.w),
                   pack_bf2(x3.x, x3.y), pack_bf2(x3.z, x3.w)};
      uint4 ub0 = {pack_bf2(w0.x, w0.y), pack_bf2(w0.z, w0.w),
                   pack_bf2(w1.x, w1.y), pack_bf2(w1.z, w1.w)};
      uint4 ub1 = {pack_bf2(w2.x, w2.y), pack_bf2(w2.z, w2.w),
                   pack_bf2(w3.x, w3.y), pack_bf2(w3.z, w3.w)};
      *(uint4*)&As[row * KP + (tq << 4)]     = ua0;
      *(uint4*)&As[row * KP + (tq << 4) + 8] = ua1;
      *(uint4*)&Bs[row * KP + (tq << 4)]     = ub0;
      *(uint4*)&Bs[row * KP + (tq << 4) + 8] = ub1;
    }
    __syncthreads();
#pragma unroll
    for (int kk = 0; kk < 2; ++kk) {
      bf16x8 af[4], bfr[4];
#pragma unroll
      for (int i = 0; i < 4; ++i)
        af[i] = *(const bf16x8*)&As[(wy * 64 + i * 16 + l16) * KP + kk * 32 + quad * 8];
#pragma unroll
      for (int j = 0; j < 4; ++j)
        bfr[j] = *(const bf16x8*)&Bs[(wx * 64 + j * 16 + l16) * KP + kk * 32 + quad * 8];
#pragma unroll
      for (int i = 0; i < 4; ++i)
#pragma unroll
        for (int j = 0; j < 4; ++j)
          acc[i][j] = __builtin_amdgcn_mfma_f32_16x16x32_bf16(af[i], bfr[j], acc[i][j], 0, 0, 0);
    }
    __syncthreads();
  }

  float bj[4];
#pragma unroll
  for (int j = 0; j < 4; ++j) bj[j] = bias[wx * 64 + j * 16 + l16];
#pragma unroll
  for (int i = 0; i < 4; ++i) {
#pragma unroll
    for (int r = 0; r < 4; ++r) {
      const int row = n0 + wy * 64 + i * 16 + quad * 4 + r;
      unsigned short* dst =
          (unsigned short*)(mat + (size_t)row * C_ + 4) + c0 + wx * 64 + l16;
#pragma unroll
      for (int j = 0; j < 4; ++j) dst[j * 16] = f2bf(acc[i][j][r] + bj[j]);
    }
  }
}

// ---------------------------------------------------------------------------
// Standalone epilogue (FALLBACK path only). v3 structure + NT stores.
// ---------------------------------------------------------------------------
__global__ __launch_bounds__(512) void epilogue_kernel(
    const int* __restrict__ pY, const int* __restrict__ Yf,
    float* __restrict__ logp, float* __restrict__ mat)
{
  const int w    = threadIdx.x >> 6;
  const int lane = threadIdx.x & 63;
  const int n    = (blockIdx.x << 3) + w;
  float* row = mat + (size_t)n * C_;
  const unsigned short* lg = (const unsigned short*)(row + 4);  // 2048 bf16

  const int py = pY[n];
  const int y  = Yf[n];

  uint2 u[8];
#pragma unroll
  for (int i = 0; i < 8; ++i)
    u[i] = *(const uint2*)(lg + (i << 8) + (lane << 2));   // 8B aligned
  const float z = row[0];
  const int ih = min(max(y - 2, 0), FP_ - 1);
  const int ir = min(max(y - 2 - FP_, 0), SP_ - 1);
  const float lh = bf2f(lg[ih]);
  const float lr = bf2f(lg[FP_ + ir]);

  float e[32];
  float sh = 0.f, sr = 0.f;
#pragma unroll
  for (int i = 0; i < 8; ++i) {
    const float e0 = __expf(bf2f((unsigned short)(u[i].x & 0xffffu)));
    const float e1 = __expf(bf2f((unsigned short)(u[i].x >> 16)));
    const float e2 = __expf(bf2f((unsigned short)(u[i].y & 0xffffu)));
    const float e3 = __expf(bf2f((unsigned short)(u[i].y >> 16)));
    e[4 * i + 0] = e0; e[4 * i + 1] = e1; e[4 * i + 2] = e2; e[4 * i + 3] = e3;
    if (i < 4) sh += e0 + e1 + e2 + e3;
    else       sr += e0 + e1 + e2 + e3;
  }
#pragma unroll
  for (int o = 32; o; o >>= 1) sh += __shfl_xor(sh, o);
#pragma unroll
  for (int o = 32; o; o >>= 1) sr += __shfl_xor(sr, o);
  const float Sh = sh, Sr = sr;

  asm volatile("s_waitcnt vmcnt(0)" ::: "memory");

  const float sig = 1.f / (1.f + __expf(-z));
  const float ne  = 1.f - sig;
  const float sch = (py == 1) ? ne / Sh : 0.f;
  const float scr = (py == 2) ? ne / Sr : 0.f;
#pragma unroll
  for (int i = 0; i < 8; ++i) {
    const float sc = (i < 4) ? sch : scr;
    f2* wp = (f2*)(row + 2 + (i << 8) + (lane << 2));  // 8B aligned
    f2 v0 = {e[4 * i + 0] * sc, e[4 * i + 1] * sc};
    f2 v1 = {e[4 * i + 2] * sc, e[4 * i + 3] * sc};
    __builtin_nontemporal_store(v0, wp);
    __builtin_nontemporal_store(v1, wp + 1);
  }
  if (lane == 0) {
    const float ev = (py == 0) ? sig : 0.f;
    row[0] = ev;
    row[1] = ev;
    const float l1p   = log1pf(__expf(-fabsf(z)));
    const float sp_z  = fmaxf(z, 0.f)  + l1p;
    const float sp_mz = fmaxf(-z, 0.f) + l1p;
    float lp;
    if      (py == 0) lp = -sp_mz;
    else if (py == 1) lp = (lh - __logf(Sh)) - sp_z;
    else if (py == 2) lp = (lr - __logf(Sr)) - sp_z;
    else              lp = 0.f;
    logp[n] = lp;
  }
}

// ---------------------------------------------------------------------------
extern "C" void kernel_launch(void* const* d_in, const int* in_sizes, int n_in,
                              void* d_out, int out_size, void* d_ws, size_t ws_size,
                              hipStream_t stream) {
  const float* X     = (const float*)d_in[0];
  const int*   pY    = (const int*)  d_in[1];
  const int*   Y     = (const int*)  d_in[2];
  const float* W_end = (const float*)d_in[3];
  const float* b_end = (const float*)d_in[4];
  const float* W_hcw = (const float*)d_in[5];
  const float* b_hcw = (const float*)d_in[6];
  const float* W_roo = (const float*)d_in[7];
  const float* b_roo = (const float*)d_in[8];

  float* out  = (float*)d_out;
  float* logp = out;              // [16384]
  float* mat  = out + N_TOK;      // [16384 x 2050], doubles as logit scratch

  const size_t xb_bytes = (size_t)N_TOK * H_ * 2;          // 67,108,864
  const size_t wb_bytes = (size_t)(FP_ + SP_) * H_ * 2;    //  8,388,608

  if (ws_size >= xb_bytes + wb_bytes) {
    unsigned short* Xb = (unsigned short*)d_ws;
    unsigned short* Wb = (unsigned short*)((char*)d_ws + xb_bytes);
    convert_kernel<<<(N_TOK + FP_ + SP_) / 4, 256, 0, stream>>>(
        X, W_hcw, W_roo, W_end, b_end, Xb, Wb, mat);
    gemm_lds_kernel<<<2048, 256, 0, stream>>>(
        Xb, Wb, b_hcw, b_roo, pY, Y, logp, mat);
    // epilogue fused into the GEMM via panel tickets
  } else {
    dim3 g(2048 / BN, N_TOK / BM);  // 16 x 128 blocks
    end_head_kernel<<<N_TOK / 4, 256, 0, stream>>>(X, W_end, b_end, mat);
    logits_gemm_fused<<<g, 256, 0, stream>>>(X, W_hcw, W_roo, b_hcw, b_roo, mat);
    epilogue_kernel<<<N_TOK / 8, 512, 0, stream>>>(pY, Y, logp, mat);
  }
}

// Round 8
// 420.335 us; speedup vs baseline: 2.5943x; 2.5943x over previous
//
#include <hip/hip_runtime.h>
#include <hip/hip_bf16.h>
#include <cstddef>
#include <cstdint>

// Problem constants (fixed by the reference)
#define N_TOK 16384     // B*S = 32*512
#define H_    2048
#define FP_   1024
#define SP_   1024
#define C_    2050      // 2 + FP + SP, prob_all row stride

#define BM 128
#define BN 128
#define BK 64
#define KP 72           // padded stride for the FALLBACK fused kernel only

typedef short bf16x8 __attribute__((ext_vector_type(8)));  // 8 bf16 = 4 VGPRs
typedef float f32x4  __attribute__((ext_vector_type(4)));  // 4 fp32 acc
typedef float f4     __attribute__((ext_vector_type(4)));  // for nt load
typedef float f2     __attribute__((ext_vector_type(2)));  // for nt store

// 8-byte-aligned 16B vector types (mat rows alternate 8/16B base alignment)
typedef uint4 u4a8 __attribute__((aligned(8)));
typedef f4    f4a8 __attribute__((aligned(8)));

__device__ __forceinline__ unsigned pack_bf2(float a, float b) {
  __hip_bfloat16 x = __float2bfloat16(a);
  __hip_bfloat16 y = __float2bfloat16(b);
  unsigned short ux, uy;
  __builtin_memcpy(&ux, &x, 2);
  __builtin_memcpy(&uy, &y, 2);
  return (unsigned)ux | ((unsigned)uy << 16);
}

__device__ __forceinline__ unsigned short f2bf(float f) {
  __hip_bfloat16 h = __float2bfloat16(f);
  unsigned short u;
  __builtin_memcpy(&u, &h, 2);
  return u;
}

__device__ __forceinline__ float bf2f(unsigned short u) {
  unsigned v = (unsigned)u << 16;
  float f;
  __builtin_memcpy(&f, &v, 4);
  return f;
}

// ---------------------------------------------------------------------------
// FAST PATH kernel 1: fp32 -> bf16 pre-convert of X (rows 0..16383) and
// W_hcw|W_roo (rows 16384..18431) into d_ws, fusing the end-head dot
// (fp32-exact) into the X pass. NT loads on read-once fp32 sources.
// (r6 configuration, reverted: no ticket zeroing.)
// ---------------------------------------------------------------------------
__global__ __launch_bounds__(256) void convert_kernel(
    const float* __restrict__ X,
    const float* __restrict__ W_hcw, const float* __restrict__ W_roo,
    const float* __restrict__ W_end, const float* __restrict__ b_end,
    unsigned short* __restrict__ Xb, unsigned short* __restrict__ Wb,
    float* __restrict__ mat)
{
  const int wave = threadIdx.x >> 6;
  const int lane = threadIdx.x & 63;
  const int row  = (blockIdx.x << 2) + wave;
  const bool isX = row < N_TOK;
  const float* src;
  unsigned short* dst;
  if (isX) {
    src = X + (size_t)row * H_;
    dst = Xb + (size_t)row * H_;
  } else {
    const int m = row - N_TOK;
    src = (m < FP_) ? (W_hcw + (size_t)m * H_) : (W_roo + (size_t)(m - FP_) * H_);
    dst = Wb + (size_t)m * H_;
  }
  float s = 0.f;
#pragma unroll
  for (int i = 0; i < 8; ++i) {
    const int e = (lane << 2) + (i << 8);      // lane*4 + i*256: coalesced
    f4 v = __builtin_nontemporal_load((const f4*)(src + e));
    uint2 p;
    p.x = pack_bf2(v[0], v[1]);
    p.y = pack_bf2(v[2], v[3]);
    *(uint2*)(dst + e) = p;                     // Xb/Wb re-read by GEMM: cached
    if (isX) {                                  // wave-uniform branch
      float4 w = *(const float4*)(W_end + e);   // 8 KB, reused: cached
      s += v[0] * w.x + v[1] * w.y + v[2] * w.z + v[3] * w.w;
    }
  }
  if (isX) {
#pragma unroll
    for (int o = 32; o; o >>= 1) s += __shfl_xor(s, o);
    if (lane == 0) mat[(size_t)row * C_] = s + b_end[0];
  }
}

// ---------------------------------------------------------------------------
// FAST PATH kernel 2: bf16 MFMA GEMM (proven 128^2 2-phase structure; r6
// configuration, reverted verbatim). Probes closed as null/negative at this
// shape: 8-phase coarse (r2), 8-phase fine (r3), XCD-swizzle FETCH-null (r6),
// ticket-fused epilogue (r7: device-scope fences destroy L2 -> 5.7% MfmaUtil).
// C-tile written as PACKED BF16 logits at float-offset 4 of each mat row.
// ---------------------------------------------------------------------------
__global__ __launch_bounds__(256) void gemm_lds_kernel(
    const unsigned short* __restrict__ Xb, const unsigned short* __restrict__ Wb,
    const float* __restrict__ b_hcw, const float* __restrict__ b_roo,
    float* __restrict__ mat)
{
  __shared__ __align__(16) unsigned short As[BM * BK];   // 16 KB
  __shared__ __align__(16) unsigned short Bs[BN * BK];   // 16 KB

  const int bid = blockIdx.x;              // 0..2047
  const int xcd = bid & 7;
  const int loc = bid >> 3;
  const int c0 = (((xcd << 1) | (loc & 1))) * BN;   // col-tile 0..15
  const int n0 = (loc >> 1) * BM;                    // row-panel 0..127
  const float* bias = (c0 < FP_) ? (b_hcw + c0) : (b_roo + (c0 - FP_));

  const int t    = threadIdx.x;
  const int wave = t >> 6;
  const int lane = t & 63;
  const int wy   = wave >> 1;
  const int wx   = wave & 1;
  const int quad = lane >> 4;
  const int l16  = lane & 15;

  // staging map: LDS flat byte f = r*4096 + t*16 -> (row = r*32 + t/8,
  // pos = t&7). That slot must hold global chunk pos ^ (row&7).
  const int srow   = t >> 3;                       // 0..31
  const int gchunk = (t & 7) ^ (srow & 7);         // swizzled global chunk
  const unsigned short* gA = Xb + (size_t)(n0 + srow) * H_ + (gchunk << 3);
  const unsigned short* gB = Wb + (size_t)(c0 + srow) * H_ + (gchunk << 3);

  f32x4 acc[4][4];
#pragma unroll
  for (int i = 0; i < 4; ++i)
#pragma unroll
    for (int j = 0; j < 4; ++j)
#pragma unroll
      for (int r = 0; r < 4; ++r) acc[i][j][r] = 0.f;

  for (int k0 = 0; k0 < H_; k0 += BK) {
#pragma unroll
    for (int r = 0; r < 4; ++r) {
      __builtin_amdgcn_global_load_lds(
          (const __attribute__((address_space(1))) unsigned int*)(gA + (size_t)(r * 32) * H_ + k0),
          (__attribute__((address_space(3))) unsigned int*)(&As[(r * 32 + srow) * BK + ((t & 7) << 3)]),
          16, 0, 0);
      __builtin_amdgcn_global_load_lds(
          (const __attribute__((address_space(1))) unsigned int*)(gB + (size_t)(r * 32) * H_ + k0),
          (__attribute__((address_space(3))) unsigned int*)(&Bs[(r * 32 + srow) * BK + ((t & 7) << 3)]),
          16, 0, 0);
    }
    __syncthreads();   // drains vmcnt before barrier (compiler-enforced)

#pragma unroll
    for (int kk = 0; kk < 2; ++kk) {
      bf16x8 af[4], bfr[4];
      const int sw = l16 & 7;                      // row&7 for both A and B rows
#pragma unroll
      for (int i = 0; i < 4; ++i) {
        const int pos = ((kk << 2) + quad) ^ sw;
        af[i] = *(const bf16x8*)&As[(wy * 64 + i * 16 + l16) * BK + (pos << 3)];
      }
#pragma unroll
      for (int j = 0; j < 4; ++j) {
        const int pos = ((kk << 2) + quad) ^ sw;
        bfr[j] = *(const bf16x8*)&Bs[(wx * 64 + j * 16 + l16) * BK + (pos << 3)];
      }
#pragma unroll
      for (int i = 0; i < 4; ++i)
#pragma unroll
        for (int j = 0; j < 4; ++j)
          acc[i][j] = __builtin_amdgcn_mfma_f32_16x16x32_bf16(af[i], bfr[j], acc[i][j], 0, 0, 0);
    }
    __syncthreads();
  }

  // C/D layout: col=lane&15, row=quad*4+reg (m89-verified). Store bf16.
  float bj[4];
#pragma unroll
  for (int j = 0; j < 4; ++j) bj[j] = bias[wx * 64 + j * 16 + l16];
#pragma unroll
  for (int i = 0; i < 4; ++i) {
#pragma unroll
    for (int r = 0; r < 4; ++r) {
      const int row = n0 + wy * 64 + i * 16 + quad * 4 + r;
      unsigned short* dst =
          (unsigned short*)(mat + (size_t)row * C_ + 4) + c0 + wx * 64 + l16;
#pragma unroll
      for (int j = 0; j < 4; ++j) dst[j * 16] = f2bf(acc[i][j][r] + bj[j]);
    }
  }
}

// ---------------------------------------------------------------------------
// FALLBACK kernels (used only if ws_size is too small). Same bf16-logit
// output convention as the fast path so one epilogue serves both.
// ---------------------------------------------------------------------------
__global__ __launch_bounds__(256) void end_head_kernel(
    const float* __restrict__ X, const float* __restrict__ W_end,
    const float* __restrict__ b_end, float* __restrict__ mat)
{
  const int wave = threadIdx.x >> 6;
  const int lane = threadIdx.x & 63;
  const int n = (blockIdx.x << 2) + wave;
  const float* x = X + (size_t)n * H_;
  float s = 0.f;
#pragma unroll
  for (int i = 0; i < 8; ++i) {
    const int e = (lane + (i << 6)) << 2;
    float4 xv = *(const float4*)(x + e);
    float4 wv = *(const float4*)(W_end + e);
    s += xv.x * wv.x + xv.y * wv.y + xv.z * wv.z + xv.w * wv.w;
  }
#pragma unroll
  for (int o = 32; o; o >>= 1) s += __shfl_xor(s, o);
  if (lane == 0) mat[(size_t)n * C_] = s + b_end[0];
}

__global__ __launch_bounds__(256) void logits_gemm_fused(
    const float* __restrict__ X,
    const float* __restrict__ W_hcw, const float* __restrict__ W_roo,
    const float* __restrict__ b_hcw, const float* __restrict__ b_roo,
    float* __restrict__ mat)
{
  __shared__ __align__(16) unsigned short As[BM * KP];
  __shared__ __align__(16) unsigned short Bs[BN * KP];

  const int c0 = blockIdx.x * BN;
  const int n0 = blockIdx.y * BM;
  const float* Wbase = (c0 < FP_) ? (W_hcw + (size_t)c0 * H_)
                                  : (W_roo + (size_t)(c0 - FP_) * H_);
  const float* bias  = (c0 < FP_) ? (b_hcw + c0) : (b_roo + (c0 - FP_));

  const int t    = threadIdx.x;
  const int wave = t >> 6;
  const int lane = t & 63;
  const int wy   = wave >> 1;
  const int wx   = wave & 1;
  const int quad = lane >> 4;
  const int l16  = lane & 15;
  const int tq = t & 3;
  const int tr = t >> 2;

  f32x4 acc[4][4];
#pragma unroll
  for (int i = 0; i < 4; ++i)
#pragma unroll
    for (int j = 0; j < 4; ++j)
#pragma unroll
      for (int r = 0; r < 4; ++r) acc[i][j][r] = 0.f;

  for (int k0 = 0; k0 < H_; k0 += BK) {
#pragma unroll
    for (int p = 0; p < 2; ++p) {
      const int row = tr + (p << 6);
      const float4* xs = (const float4*)(X + (size_t)(n0 + row) * H_ + k0 + (tq << 4));
      const float4* ws = (const float4*)(Wbase + (size_t)row * H_ + k0 + (tq << 4));
      float4 x0 = xs[0], x1 = xs[1], x2 = xs[2], x3 = xs[3];
      float4 w0 = ws[0], w1 = ws[1], w2 = ws[2], w3 = ws[3];
      uint4 ua0 = {pack_bf2(x0.x, x0.y), pack_bf2(x0.z, x0.w),
                   pack_bf2(x1.x, x1.y), pack_bf2(x1.z, x1.w)};
      uint4 ua1 = {pack_bf2(x2.x, x2.y), pack_bf2(x2.z, x2.w),
                   pack_bf2(x3.x, x3.y), pack_bf2(x3.z, x3.w)};
      uint4 ub0 = {pack_bf2(w0.x, w0.y), pack_bf2(w0.z, w0.w),
                   pack_bf2(w1.x, w1.y), pack_bf2(w1.z, w1.w)};
      uint4 ub1 = {pack_bf2(w2.x, w2.y), pack_bf2(w2.z, w2.w),
                   pack_bf2(w3.x, w3.y), pack_bf2(w3.z, w3.w)};
      *(uint4*)&As[row * KP + (tq << 4)]     = ua0;
      *(uint4*)&As[row * KP + (tq << 4) + 8] = ua1;
      *(uint4*)&Bs[row * KP + (tq << 4)]     = ub0;
      *(uint4*)&Bs[row * KP + (tq << 4) + 8] = ub1;
    }
    __syncthreads();
#pragma unroll
    for (int kk = 0; kk < 2; ++kk) {
      bf16x8 af[4], bfr[4];
#pragma unroll
      for (int i = 0; i < 4; ++i)
        af[i] = *(const bf16x8*)&As[(wy * 64 + i * 16 + l16) * KP + kk * 32 + quad * 8];
#pragma unroll
      for (int j = 0; j < 4; ++j)
        bfr[j] = *(const bf16x8*)&Bs[(wx * 64 + j * 16 + l16) * KP + kk * 32 + quad * 8];
#pragma unroll
      for (int i = 0; i < 4; ++i)
#pragma unroll
        for (int j = 0; j < 4; ++j)
          acc[i][j] = __builtin_amdgcn_mfma_f32_16x16x32_bf16(af[i], bfr[j], acc[i][j], 0, 0, 0);
    }
    __syncthreads();
  }

  float bj[4];
#pragma unroll
  for (int j = 0; j < 4; ++j) bj[j] = bias[wx * 64 + j * 16 + l16];
#pragma unroll
  for (int i = 0; i < 4; ++i) {
#pragma unroll
    for (int r = 0; r < 4; ++r) {
      const int row = n0 + wy * 64 + i * 16 + quad * 4 + r;
      unsigned short* dst =
          (unsigned short*)(mat + (size_t)row * C_ + 4) + c0 + wx * 64 + l16;
#pragma unroll
      for (int j = 0; j < 4; ++j) dst[j * 16] = f2bf(acc[i][j][r] + bj[j]);
    }
  }
}

// ---------------------------------------------------------------------------
// Epilogue v4 (NEW this round): v3 structure with 16B memory ops.
// One wave per token, zero barriers/LDS. Iteration i covers classes
// [i*512, (i+1)*512); lane owns 8 consecutive classes:
//   reads:  4x 16B at lg + i*1024B + lane*16B  (contiguous 1KB / instr)
//   writes: 8x 16B NT at row+2 + i*2048B + lane*32B (contiguous 2KB / pair)
// (Halves memory instruction count vs v3's uint2/f2.) Rows alternate 8/16B
// base alignment -> aligned(8) vector types (gfx9 global 16B ops need only
// dword alignment). 4 tokens per 256-thread block -> 4096 blocks.
// In-place overwrite is same-wave only; fenced with s_waitcnt vmcnt(0).
// ---------------------------------------------------------------------------
__global__ __launch_bounds__(256) void epilogue_kernel(
    const int* __restrict__ pY, const int* __restrict__ Yf,
    float* __restrict__ logp, float* __restrict__ mat)
{
  const int w    = threadIdx.x >> 6;
  const int lane = threadIdx.x & 63;
  const int n    = (blockIdx.x << 2) + w;
  float* row = mat + (size_t)n * C_;
  const unsigned short* lg = (const unsigned short*)(row + 4);  // 2048 bf16

  const int py = pY[n];
  const int y  = Yf[n];

  // ---- read phase: iteration i covers classes [i*512, i*512+512) ---------
  u4a8 u[4];
#pragma unroll
  for (int i = 0; i < 4; ++i)
    u[i] = *(const u4a8*)(lg + (i << 9) + (lane << 3));
  const float z = row[0];
  const int ih = min(max(y - 2, 0), FP_ - 1);
  const int ir = min(max(y - 2 - FP_, 0), SP_ - 1);
  const float lh = bf2f(lg[ih]);          // same-address broadcast load
  const float lr = bf2f(lg[FP_ + ir]);

  // ---- exp + two full-wave butterfly sums (i<2 = hcw, i>=2 = roo) --------
  float e[32];
  float sh = 0.f, sr = 0.f;
#pragma unroll
  for (int i = 0; i < 4; ++i) {
    unsigned dw[4] = {u[i].x, u[i].y, u[i].z, u[i].w};
    float part = 0.f;
#pragma unroll
    for (int d = 0; d < 4; ++d) {
      const float lo = __expf(bf2f((unsigned short)(dw[d] & 0xffffu)));
      const float hi = __expf(bf2f((unsigned short)(dw[d] >> 16)));
      e[8 * i + 2 * d]     = lo;
      e[8 * i + 2 * d + 1] = hi;
      part += lo + hi;
    }
    if (i < 2) sh += part;
    else       sr += part;
  }
#pragma unroll
  for (int o = 32; o; o >>= 1) sh += __shfl_xor(sh, o);
#pragma unroll
  for (int o = 32; o; o >>= 1) sr += __shfl_xor(sr, o);
  const float Sh = sh, Sr = sr;

  // all reads (incl. lh/lr/z) must be in regs before in-place writes below
  asm volatile("s_waitcnt vmcnt(0)" ::: "memory");

  // ---- write phase (non-temporal: probs never re-read on device) ---------
  const float sig = 1.f / (1.f + __expf(-z));
  const float ne  = 1.f - sig;
  const float sch = (py == 1) ? ne / Sh : 0.f;
  const float scr = (py == 2) ? ne / Sr : 0.f;
#pragma unroll
  for (int i = 0; i < 4; ++i) {
    const float sc = (i < 2) ? sch : scr;
    f4a8* wp = (f4a8*)(row + 2 + (i << 9) + (lane << 3));
    f4a8 v0 = {e[8 * i + 0] * sc, e[8 * i + 1] * sc,
               e[8 * i + 2] * sc, e[8 * i + 3] * sc};
    f4a8 v1 = {e[8 * i + 4] * sc, e[8 * i + 5] * sc,
               e[8 * i + 6] * sc, e[8 * i + 7] * sc};
    __builtin_nontemporal_store(v0, wp);
    __builtin_nontemporal_store(v1, wp + 1);
  }
  if (lane == 0) {
    const float ev = (py == 0) ? sig : 0.f;
    row[0] = ev;
    row[1] = ev;
    const float l1p   = log1pf(__expf(-fabsf(z)));
    const float sp_z  = fmaxf(z, 0.f)  + l1p;
    const float sp_mz = fmaxf(-z, 0.f) + l1p;
    float lp;
    if      (py == 0) lp = -sp_mz;
    else if (py == 1) lp = (lh - __logf(Sh)) - sp_z;
    else if (py == 2) lp = (lr - __logf(Sr)) - sp_z;
    else              lp = 0.f;
    logp[n] = lp;
  }
}

// ---------------------------------------------------------------------------
extern "C" void kernel_launch(void* const* d_in, const int* in_sizes, int n_in,
                              void* d_out, int out_size, void* d_ws, size_t ws_size,
                              hipStream_t stream) {
  const float* X     = (const float*)d_in[0];
  const int*   pY    = (const int*)  d_in[1];
  const int*   Y     = (const int*)  d_in[2];
  const float* W_end = (const float*)d_in[3];
  const float* b_end = (const float*)d_in[4];
  const float* W_hcw = (const float*)d_in[5];
  const float* b_hcw = (const float*)d_in[6];
  const float* W_roo = (const float*)d_in[7];
  const float* b_roo = (const float*)d_in[8];

  float* out  = (float*)d_out;
  float* logp = out;              // [16384]
  float* mat  = out + N_TOK;      // [16384 x 2050], doubles as logit scratch

  const size_t xb_bytes = (size_t)N_TOK * H_ * 2;          // 67,108,864
  const size_t wb_bytes = (size_t)(FP_ + SP_) * H_ * 2;    //  8,388,608

  if (ws_size >= xb_bytes + wb_bytes) {
    unsigned short* Xb = (unsigned short*)d_ws;
    unsigned short* Wb = (unsigned short*)((char*)d_ws + xb_bytes);
    convert_kernel<<<(N_TOK + FP_ + SP_) / 4, 256, 0, stream>>>(
        X, W_hcw, W_roo, W_end, b_end, Xb, Wb, mat);
    gemm_lds_kernel<<<2048, 256, 0, stream>>>(Xb, Wb, b_hcw, b_roo, mat);
  } else {
    dim3 g(2048 / BN, N_TOK / BM);  // 16 x 128 blocks
    end_head_kernel<<<N_TOK / 4, 256, 0, stream>>>(X, W_end, b_end, mat);
    logits_gemm_fused<<<g, 256, 0, stream>>>(X, W_hcw, W_roo, b_hcw, b_roo, mat);
  }
  epilogue_kernel<<<N_TOK / 4, 256, 0, stream>>>(pY, Y, logp, mat);
}